// Round 1
// baseline (3290.454 us; speedup 1.0000x reference)
//
#include <hip/hip_runtime.h>
#include <cstdint>

#define BATCH 4
#define DIMC 384
#define CINC 387
#define COMPC 64
#define GSZ 224

// ---------- antialiased bilinear resize (matches jax.image.resize antialias=True) ----------
__global__ void resize_kernel(const float* __restrict__ g, float* __restrict__ out,
                              int h, int w, int inv_scale) {
  int idx = blockIdx.x * blockDim.x + threadIdx.x;
  int total = BATCH * 3 * h * w;
  if (idx >= total) return;
  int j = idx % w; int t = idx / w;
  int i = t % h; t /= h;            // t = n*3 + ch
  float ks = (float)inv_scale;      // kernel_scale = inv_scale (downsample, antialias)
  float sy = (i + 0.5f) * ks - 0.5f;
  float sx = (j + 0.5f) * ks - 0.5f;
  int y0 = (int)ceilf(sy - ks); if (y0 < 0) y0 = 0;
  int y1 = (int)floorf(sy + ks); if (y1 > GSZ - 1) y1 = GSZ - 1;
  int x0 = (int)ceilf(sx - ks); if (x0 < 0) x0 = 0;
  int x1 = (int)floorf(sx + ks); if (x1 > GSZ - 1) x1 = GSZ - 1;
  const float* gp = g + (size_t)t * GSZ * GSZ;
  float wsx = 0.f;
  for (int x = x0; x <= x1; ++x) wsx += fmaxf(0.f, 1.f - fabsf(sx - (float)x) / ks);
  float acc = 0.f, wsy = 0.f;
  for (int y = y0; y <= y1; ++y) {
    float wy = fmaxf(0.f, 1.f - fabsf(sy - (float)y) / ks);
    wsy += wy;
    if (wy > 0.f) {
      const float* rp = gp + (size_t)y * GSZ;
      float row = 0.f;
      for (int x = x0; x <= x1; ++x) {
        float wx = fmaxf(0.f, 1.f - fabsf(sx - (float)x) / ks);
        row += wx * rp[x];
      }
      acc += wy * row;
    }
  }
  out[idx] = acc / (wsx * wsy);
}

// ---------- 1x1 conv 387->64: thread per pixel, 64 accumulators (src read once) ----------
__global__ void comp_conv_kernel(const float* __restrict__ src, const float* __restrict__ g,
                                 const float* __restrict__ cw, const float* __restrict__ cb,
                                 float* __restrict__ comp, int h, int w) {
  int p = blockIdx.x * blockDim.x + threadIdx.x;
  int hw = h * w;
  int n = blockIdx.y;
  if (p >= hw) return;
  float acc[COMPC];
  #pragma unroll
  for (int co = 0; co < COMPC; ++co) acc[co] = cb[co];
  const float* sp = src + (size_t)n * DIMC * hw + p;
  for (int ci = 0; ci < DIMC; ++ci) {
    float v = sp[(size_t)ci * hw];
    #pragma unroll
    for (int co = 0; co < COMPC; ++co) acc[co] += cw[co * CINC + ci] * v;
  }
  const float* gp = g + (size_t)n * 3 * hw + p;
  #pragma unroll
  for (int ci = 0; ci < 3; ++ci) {
    float v = gp[(size_t)ci * hw];
    #pragma unroll
    for (int co = 0; co < COMPC; ++co) acc[co] += cw[co * CINC + DIMC + ci] * v;
  }
  float* op = comp + (size_t)n * COMPC * hw + p;
  for (int co = 0; co < COMPC; ++co) op[(size_t)co * hw] = acc[co];
}

// ---------- 3x3 conv 64->36 + pixel_shuffle(2) + softmax over 9 -> mask [n][2h][2w][9] ----------
__global__ void enc_mask_kernel(const float* __restrict__ comp, const float* __restrict__ ew,
                                const float* __restrict__ eb, float* __restrict__ mask,
                                int h, int w) {
  int p = blockIdx.x * blockDim.x + threadIdx.x;
  int hw = h * w;
  int n = blockIdx.y;
  if (p >= hw) return;
  int i = p / w, j = p % w;
  float acc[36];
  #pragma unroll
  for (int c = 0; c < 36; ++c) acc[c] = eb[c];
  const float* cpn = comp + (size_t)n * COMPC * hw;
  for (int ci = 0; ci < COMPC; ++ci) {
    const float* cp = cpn + (size_t)ci * hw;
    #pragma unroll
    for (int di = 0; di < 3; ++di) {
      int y = i + di - 1;
      if (y < 0 || y >= h) continue;
      #pragma unroll
      for (int dj = 0; dj < 3; ++dj) {
        int x = j + dj - 1;
        if (x < 0 || x >= w) continue;
        float v = cp[(size_t)y * w + x];
        const float* wp = ew + (size_t)ci * 9 + di * 3 + dj;  // ew[co][ci][di][dj]
        #pragma unroll
        for (int co = 0; co < 36; ++co) acc[co] += wp[(size_t)co * COMPC * 9] * v;
      }
    }
  }
  int H = 2 * h, W = 2 * w;
  #pragma unroll
  for (int pp = 0; pp < 2; ++pp) {
    #pragma unroll
    for (int q = 0; q < 2; ++q) {
      float m = -1e30f;
      #pragma unroll
      for (int k = 0; k < 9; ++k) m = fmaxf(m, acc[k * 4 + pp * 2 + q]);
      float e[9]; float s = 0.f;
      #pragma unroll
      for (int k = 0; k < 9; ++k) { e[k] = __expf(acc[k * 4 + pp * 2 + q] - m); s += e[k]; }
      float inv = 1.f / s;
      float* mp = mask + (((size_t)n * H + (2 * i + pp)) * W + (2 * j + q)) * 9;
      #pragma unroll
      for (int k = 0; k < 9; ++k) mp[k] = e[k] * inv;
    }
  }
}

// ---------- CARAFE reassembly: out[n,c,2i+p,2j+q] = sum_k src[n,c,i-1+k/3,j-1+k%3]*mask[...,k] ----------
__global__ void carafe_kernel(const float* __restrict__ src, const float* __restrict__ mask,
                              float* __restrict__ out, int h, int w) {
  int p = blockIdx.x * blockDim.x + threadIdx.x;
  int hw = h * w;
  if (p >= hw) return;
  int c0 = blockIdx.y * 4, n = blockIdx.z;
  int i = p / w, j = p % w;
  int H = 2 * h, W = 2 * w;
  float m[4][9];
  #pragma unroll
  for (int pp = 0; pp < 2; ++pp)
    #pragma unroll
    for (int q = 0; q < 2; ++q) {
      const float* mp = mask + (((size_t)n * H + (2 * i + pp)) * W + (2 * j + q)) * 9;
      #pragma unroll
      for (int k = 0; k < 9; ++k) m[pp * 2 + q][k] = mp[k];
    }
  #pragma unroll
  for (int cc = 0; cc < 4; ++cc) {
    int c = c0 + cc;
    const float* sp = src + ((size_t)(n * DIMC + c)) * hw;
    float v[9];
    #pragma unroll
    for (int k = 0; k < 9; ++k) {
      int y = i - 1 + k / 3, x = j - 1 + k % 3;
      v[k] = (y >= 0 && y < h && x >= 0 && x < w) ? sp[(size_t)y * w + x] : 0.f;
    }
    float* op = out + ((size_t)(n * DIMC + c)) * H * W;
    #pragma unroll
    for (int pp = 0; pp < 2; ++pp) {
      float a0 = 0.f, a1 = 0.f;
      #pragma unroll
      for (int k = 0; k < 9; ++k) {
        a0 += v[k] * m[pp * 2 + 0][k];
        a1 += v[k] * m[pp * 2 + 1][k];
      }
      float2 r; r.x = a0; r.y = a1;
      *(float2*)(op + (size_t)(2 * i + pp) * W + 2 * j) = r;
    }
  }
}

// ---------- transpose proj weights [384][387] -> [387][384] for coalesced loads ----------
__global__ void transpose_w(const float* __restrict__ pw, float* __restrict__ pwT) {
  int idx = blockIdx.x * blockDim.x + threadIdx.x;
  if (idx >= DIMC * CINC) return;
  int co = idx / CINC, ci = idx % CINC;
  pwT[(size_t)ci * DIMC + co] = pw[idx];
}

// ---------- final 1x1 conv 387->384 at 224x224, IN-PLACE on d_out ----------
#define FC_PX 32
__global__ __launch_bounds__(384) void final_conv_kernel(const float* __restrict__ guid,
                                                         const float* __restrict__ pwT,
                                                         const float* __restrict__ pb,
                                                         float* out) {
  __shared__ float X[CINC][FC_PX];  // 49.5 KB
  const int HW = GSZ * GSZ;         // 50176
  int n = blockIdx.y;
  int px0 = blockIdx.x * FC_PX;
  int t = threadIdx.x;
  for (int idx = t; idx < CINC * FC_PX; idx += 384) {
    int ci = idx / FC_PX, px = idx % FC_PX;
    int p = px0 + px;
    float v;
    if (ci < DIMC) v = out[((size_t)(n * DIMC + ci)) * HW + p];
    else v = guid[((size_t)(n * 3 + (ci - DIMC))) * HW + p];
    X[ci][px] = v;
  }
  __syncthreads();
  int tco = t % 48;   // 48 groups of 8 co
  int tpx = t / 48;   // 8 groups of 4 px
  int co0 = tco * 8, lpx0 = tpx * 4;
  float acc[8][4];
  #pragma unroll
  for (int r = 0; r < 8; ++r) {
    float b = pb[co0 + r];
    #pragma unroll
    for (int q = 0; q < 4; ++q) acc[r][q] = b;
  }
  for (int ci = 0; ci < CINC; ++ci) {
    float xv[4];
    #pragma unroll
    for (int q = 0; q < 4; ++q) xv[q] = X[ci][lpx0 + q];
    const float4* wrow = (const float4*)(pwT + (size_t)ci * DIMC + co0);
    float4 w0 = wrow[0], w1 = wrow[1];
    const float wv[8] = {w0.x, w0.y, w0.z, w0.w, w1.x, w1.y, w1.z, w1.w};
    #pragma unroll
    for (int r = 0; r < 8; ++r)
      #pragma unroll
      for (int q = 0; q < 4; ++q) acc[r][q] += wv[r] * xv[q];
  }
  #pragma unroll
  for (int r = 0; r < 8; ++r) {
    float4 o; o.x = acc[r][0]; o.y = acc[r][1]; o.z = acc[r][2]; o.w = acc[r][3];
    *(float4*)(out + ((size_t)(n * DIMC + co0 + r)) * HW + px0 + lpx0) = o;
  }
}

extern "C" void kernel_launch(void* const* d_in, const int* in_sizes, int n_in,
                              void* d_out, int out_size, void* d_ws, size_t ws_size,
                              hipStream_t stream) {
  const float* source   = (const float*)d_in[0];
  const float* guidance = (const float*)d_in[1];
  const float* cw[4] = {(const float*)d_in[2],  (const float*)d_in[6],
                        (const float*)d_in[10], (const float*)d_in[14]};
  const float* cb[4] = {(const float*)d_in[3],  (const float*)d_in[7],
                        (const float*)d_in[11], (const float*)d_in[15]};
  const float* ew[4] = {(const float*)d_in[4],  (const float*)d_in[8],
                        (const float*)d_in[12], (const float*)d_in[16]};
  const float* eb[4] = {(const float*)d_in[5],  (const float*)d_in[9],
                        (const float*)d_in[13], (const float*)d_in[17]};
  const float* pw = (const float*)d_in[18];
  const float* pb = (const float*)d_in[19];
  float* out = (float*)d_out;

  float* ws = (float*)d_ws;
  float* g_buf    = ws;                     // 4*3*112*112        = 150528
  float* comp_buf = g_buf + 150528;         // 4*64*112*112       = 3211264
  float* mask_buf = comp_buf + 3211264;     // 4*224*224*9        = 1806336
  float* s2  = mask_buf + 1806336;          // 4*384*28*28        = 1204224
  float* s4  = s2 + 1204224;                // 4*384*56*56        = 4816896
  float* s8  = s4 + 4816896;                // 4*384*112*112      = 19267584
  float* pwT = s8 + 19267584;               // 387*384            = 148608

  transpose_w<<<(DIMC * CINC + 255) / 256, 256, 0, stream>>>(pw, pwT);

  const float* srcs[4] = {source, s2, s4, s8};
  float* outs[4] = {s2, s4, s8, out};
  const int hs[4] = {14, 28, 56, 112};
  for (int s = 0; s < 4; ++s) {
    int h = hs[s], w = h, hw = h * w;
    int total_r = BATCH * 3 * hw;
    resize_kernel<<<(total_r + 255) / 256, 256, 0, stream>>>(guidance, g_buf, h, w, GSZ / h);
    comp_conv_kernel<<<dim3((hw + 255) / 256, BATCH), 256, 0, stream>>>(
        srcs[s], g_buf, cw[s], cb[s], comp_buf, h, w);
    enc_mask_kernel<<<dim3((hw + 255) / 256, BATCH), 256, 0, stream>>>(
        comp_buf, ew[s], eb[s], mask_buf, h, w);
    carafe_kernel<<<dim3((hw + 255) / 256, DIMC / 4, BATCH), 256, 0, stream>>>(
        srcs[s], mask_buf, outs[s], h, w);
  }
  final_conv_kernel<<<dim3((GSZ * GSZ) / FC_PX, BATCH), 384, 0, stream>>>(guidance, pwT, pb, out);
}

// Round 2
// 2136.728 us; speedup vs baseline: 1.5399x; 1.5399x over previous
//
#include <hip/hip_runtime.h>
#include <cstdint>

#define BATCH 4
#define DIMC 384
#define CINC 387
#define COMPC 64
#define GSZ 224

typedef __attribute__((ext_vector_type(8))) short bf16x8;
typedef __attribute__((ext_vector_type(4))) float f32x4;

static __device__ __forceinline__ unsigned short f2bf(float x) {
  unsigned int u = __float_as_uint(x);
  unsigned int r = (u + 0x7fffu + ((u >> 16) & 1u)) >> 16;
  return (unsigned short)r;
}
static __device__ __forceinline__ float bf2f(unsigned short b) {
  return __uint_as_float(((unsigned int)b) << 16);
}

// ---------- antialiased bilinear resize (jax.image.resize, antialias=True) ----------
__global__ void resize_kernel(const float* __restrict__ g, float* __restrict__ out,
                              int h, int w, int inv_scale) {
  int idx = blockIdx.x * blockDim.x + threadIdx.x;
  int total = BATCH * 3 * h * w;
  if (idx >= total) return;
  int j = idx % w; int t = idx / w;
  int i = t % h; t /= h;
  float ks = (float)inv_scale;
  float sy = (i + 0.5f) * ks - 0.5f;
  float sx = (j + 0.5f) * ks - 0.5f;
  int y0 = (int)ceilf(sy - ks); if (y0 < 0) y0 = 0;
  int y1 = (int)floorf(sy + ks); if (y1 > GSZ - 1) y1 = GSZ - 1;
  int x0 = (int)ceilf(sx - ks); if (x0 < 0) x0 = 0;
  int x1 = (int)floorf(sx + ks); if (x1 > GSZ - 1) x1 = GSZ - 1;
  const float* gp = g + (size_t)t * GSZ * GSZ;
  float wsx = 0.f;
  for (int x = x0; x <= x1; ++x) wsx += fmaxf(0.f, 1.f - fabsf(sx - (float)x) / ks);
  float acc = 0.f, wsy = 0.f;
  for (int y = y0; y <= y1; ++y) {
    float wy = fmaxf(0.f, 1.f - fabsf(sy - (float)y) / ks);
    wsy += wy;
    if (wy > 0.f) {
      const float* rp = gp + (size_t)y * GSZ;
      float row = 0.f;
      for (int x = x0; x <= x1; ++x) {
        float wx = fmaxf(0.f, 1.f - fabsf(sx - (float)x) / ks);
        row += wx * rp[x];
      }
      acc += wy * row;
    }
  }
  out[idx] = acc / (wsx * wsy);
}

// ---------- weight prep ----------
__global__ void prep_cw(const float* __restrict__ c0, const float* __restrict__ c1,
                        const float* __restrict__ c2, const float* __restrict__ c3,
                        float* __restrict__ cwT) {
  int s = blockIdx.y;
  const float* cw = (s == 0) ? c0 : (s == 1) ? c1 : (s == 2) ? c2 : c3;
  int idx = blockIdx.x * 256 + threadIdx.x;
  if (idx >= CINC * COMPC) return;
  int ci = idx >> 6, co = idx & 63;
  cwT[s * (CINC * COMPC) + idx] = cw[co * CINC + ci];
}

__global__ void prep_ew(const float* __restrict__ e0, const float* __restrict__ e1,
                        const float* __restrict__ e2, const float* __restrict__ e3,
                        float* __restrict__ ewT) {
  int s = blockIdx.y;
  const float* ew = (s == 0) ? e0 : (s == 1) ? e1 : (s == 2) ? e2 : e3;
  int idx = blockIdx.x * 256 + threadIdx.x;
  if (idx >= COMPC * 9 * 4 * 9) return;
  int k = idx % 9; int r = idx / 9;
  int pos = r % 4; r /= 4;
  int tap = r % 9; int ci = r / 9;
  ewT[s * (COMPC * 9 * 4 * 9) + idx] = ew[(size_t)(k * 4 + pos) * COMPC * 9 + ci * 9 + tap];
}

#define KPAD 416
__global__ void prep_w(const float* __restrict__ pw, short* __restrict__ Whi,
                       short* __restrict__ Wlo) {
  int idx = blockIdx.x * 256 + threadIdx.x;
  if (idx >= DIMC * KPAD) return;
  int co = idx / KPAD, k = idx % KPAD;
  float v = (k < CINC) ? pw[co * CINC + k] : 0.f;
  unsigned short hb = f2bf(v);
  Whi[idx] = (short)hb;
  Wlo[idx] = (short)f2bf(v - bf2f(hb));
}

// ---------- 1x1 conv 387->64: 4 co per thread, transposed float4 weights ----------
__global__ void comp_conv_kernel(const float* __restrict__ src, const float* __restrict__ g,
                                 const float* __restrict__ cwT, const float* __restrict__ cb,
                                 float* __restrict__ comp, int h, int w) {
  int hw = h * w;
  int idx = blockIdx.x * 256 + threadIdx.x;
  if (idx >= hw * 16) return;
  int part = idx & 15, p = idx >> 4;
  int co0 = part * 4;
  int n = blockIdx.y;
  float4 acc = *(const float4*)&cb[co0];
  const float* sp = src + (size_t)n * DIMC * hw + p;
  for (int ci = 0; ci < DIMC; ++ci) {
    float v = sp[(size_t)ci * hw];
    float4 wv = *(const float4*)&cwT[ci * COMPC + co0];
    acc.x += wv.x * v; acc.y += wv.y * v; acc.z += wv.z * v; acc.w += wv.w * v;
  }
  const float* gp = g + (size_t)n * 3 * hw + p;
  #pragma unroll
  for (int ci = 0; ci < 3; ++ci) {
    float v = gp[(size_t)ci * hw];
    float4 wv = *(const float4*)&cwT[(DIMC + ci) * COMPC + co0];
    acc.x += wv.x * v; acc.y += wv.y * v; acc.z += wv.z * v; acc.w += wv.w * v;
  }
  float* op = comp + (size_t)n * COMPC * hw + p;
  op[(size_t)(co0 + 0) * hw] = acc.x;
  op[(size_t)(co0 + 1) * hw] = acc.y;
  op[(size_t)(co0 + 2) * hw] = acc.z;
  op[(size_t)(co0 + 3) * hw] = acc.w;
}

// ---------- 3x3 conv 64->36 + pixel_shuffle + softmax; 1 thread = 1 (px, position) ----------
__global__ void enc_mask_kernel(const float* __restrict__ comp, const float* __restrict__ ewT,
                                const float* __restrict__ eb, float* __restrict__ mask,
                                int h, int w) {
  int hw = h * w;
  int idx = blockIdx.x * 256 + threadIdx.x;
  if (idx >= hw * 4) return;
  int pos = idx & 3, p = idx >> 2;
  int n = blockIdx.y;
  int i = p / w, j = p % w;
  float acc[9];
  #pragma unroll
  for (int k = 0; k < 9; ++k) acc[k] = eb[k * 4 + pos];
  const float* cpn = comp + (size_t)n * COMPC * hw;
  for (int ci = 0; ci < COMPC; ++ci) {
    const float* cp = cpn + (size_t)ci * hw;
    #pragma unroll
    for (int di = 0; di < 3; ++di) {
      int y = i + di - 1;
      if (y < 0 || y >= h) continue;
      #pragma unroll
      for (int dj = 0; dj < 3; ++dj) {
        int x = j + dj - 1;
        if (x < 0 || x >= w) continue;
        float v = cp[(size_t)y * w + x];
        const float* wb = ewT + ((size_t)(ci * 9 + di * 3 + dj) * 4 + pos) * 9;
        #pragma unroll
        for (int k = 0; k < 9; ++k) acc[k] += wb[k] * v;
      }
    }
  }
  float m = -1e30f;
  #pragma unroll
  for (int k = 0; k < 9; ++k) m = fmaxf(m, acc[k]);
  float e[9]; float s = 0.f;
  #pragma unroll
  for (int k = 0; k < 9; ++k) { e[k] = __expf(acc[k] - m); s += e[k]; }
  float inv = 1.f / s;
  int pp = pos >> 1, q = pos & 1;
  int H = 2 * h, W = 2 * w;
  float* mp = mask + (((size_t)n * H + (2 * i + pp)) * W + (2 * j + q)) * 9;
  #pragma unroll
  for (int k = 0; k < 9; ++k) mp[k] = e[k] * inv;
}

// ---------- CARAFE reassembly ----------
__global__ void carafe_kernel(const float* __restrict__ src, const float* __restrict__ mask,
                              float* __restrict__ out, int h, int w) {
  int p = blockIdx.x * blockDim.x + threadIdx.x;
  int hw = h * w;
  if (p >= hw) return;
  int c0 = blockIdx.y * 4, n = blockIdx.z;
  int i = p / w, j = p % w;
  int H = 2 * h, W = 2 * w;
  float m[4][9];
  #pragma unroll
  for (int pp = 0; pp < 2; ++pp)
    #pragma unroll
    for (int q = 0; q < 2; ++q) {
      const float* mp = mask + (((size_t)n * H + (2 * i + pp)) * W + (2 * j + q)) * 9;
      #pragma unroll
      for (int k = 0; k < 9; ++k) m[pp * 2 + q][k] = mp[k];
    }
  #pragma unroll
  for (int cc = 0; cc < 4; ++cc) {
    int c = c0 + cc;
    const float* sp = src + ((size_t)(n * DIMC + c)) * hw;
    float v[9];
    #pragma unroll
    for (int k = 0; k < 9; ++k) {
      int y = i - 1 + k / 3, x = j - 1 + k % 3;
      v[k] = (y >= 0 && y < h && x >= 0 && x < w) ? sp[(size_t)y * w + x] : 0.f;
    }
    float* op = out + ((size_t)(n * DIMC + c)) * H * W;
    #pragma unroll
    for (int pp = 0; pp < 2; ++pp) {
      float a0 = 0.f, a1 = 0.f;
      #pragma unroll
      for (int k = 0; k < 9; ++k) {
        a0 += v[k] * m[pp * 2 + 0][k];
        a1 += v[k] * m[pp * 2 + 1][k];
      }
      float2 r; r.x = a0; r.y = a1;
      *(float2*)(op + (size_t)(2 * i + pp) * W + 2 * j) = r;
    }
  }
}

// ---------- final 1x1 conv 387->384 via bf16x3 MFMA, in-place on d_out ----------
// C[co, px] = W[co, k] * X[k, px];  x*w ~= xh*wh + xh*wl + xl*wh  (bf16 split)
// Block: 256 threads (4 waves), px-tile 32, K staged fully in LDS (blocked frag layout).
#define FC_KT 13           // 416 / 32
__global__ __launch_bounds__(256) void final_conv_mfma(const float* __restrict__ guid,
                                                       const short* __restrict__ Whi,
                                                       const short* __restrict__ Wlo,
                                                       const float* __restrict__ pb,
                                                       float* out) {
  __shared__ short XH[FC_KT * 2 * 512];   // 13 kt x 2 nt x (64 lanes x 8 bf16)
  __shared__ short XL[FC_KT * 2 * 512];
  const int HW = GSZ * GSZ;
  int n = blockIdx.y;
  int px0 = blockIdx.x * 32;

  // stage X (fp32 -> bf16 hi/lo) into blocked fragment layout
  for (int idx = threadIdx.x; idx < KPAD * 8; idx += 256) {
    int ci = idx >> 3, px4 = idx & 7;
    float vv[4] = {0.f, 0.f, 0.f, 0.f};
    if (ci < DIMC) {
      float4 v = *(const float4*)(out + ((size_t)(n * DIMC + ci)) * HW + px0 + px4 * 4);
      vv[0] = v.x; vv[1] = v.y; vv[2] = v.z; vv[3] = v.w;
    } else if (ci < CINC) {
      float4 v = *(const float4*)(guid + ((size_t)(n * 3 + (ci - DIMC))) * HW + px0 + px4 * 4);
      vv[0] = v.x; vv[1] = v.y; vv[2] = v.z; vv[3] = v.w;
    }
    int kt = ci >> 5, q = (ci >> 3) & 3, j = ci & 7;
    #pragma unroll
    for (int e = 0; e < 4; ++e) {
      int px = px4 * 4 + e;
      int nt = px >> 4, pxl = px & 15;
      int chunk = (kt * 2 + nt) * 64 + q * 16 + pxl;
      unsigned short hb = f2bf(vv[e]);
      XH[chunk * 8 + j] = (short)hb;
      XL[chunk * 8 + j] = (short)f2bf(vv[e] - bf2f(hb));
    }
  }
  __syncthreads();

  int wv = threadIdx.x >> 6, lane = threadIdx.x & 63;
  int lm = lane & 15, qq = lane >> 4;
  f32x4 acc[6][2];
  #pragma unroll
  for (int mt = 0; mt < 6; ++mt)
    #pragma unroll
    for (int nt = 0; nt < 2; ++nt) acc[mt][nt] = (f32x4){0.f, 0.f, 0.f, 0.f};

  for (int kt = 0; kt < FC_KT; ++kt) {
    bf16x8 bh[2], bl[2];
    #pragma unroll
    for (int nt = 0; nt < 2; ++nt) {
      int cb = ((kt * 2 + nt) * 64 + lane) * 8;
      bh[nt] = *(const bf16x8*)&XH[cb];
      bl[nt] = *(const bf16x8*)&XL[cb];
    }
    #pragma unroll
    for (int mt = 0; mt < 6; ++mt) {
      int co = wv * 96 + mt * 16 + lm;
      size_t woff = (size_t)co * KPAD + kt * 32 + qq * 8;
      bf16x8 ah = *(const bf16x8*)(Whi + woff);
      bf16x8 al = *(const bf16x8*)(Wlo + woff);
      #pragma unroll
      for (int nt = 0; nt < 2; ++nt) {
        acc[mt][nt] = __builtin_amdgcn_mfma_f32_16x16x32_bf16(ah, bh[nt], acc[mt][nt], 0, 0, 0);
        acc[mt][nt] = __builtin_amdgcn_mfma_f32_16x16x32_bf16(ah, bl[nt], acc[mt][nt], 0, 0, 0);
        acc[mt][nt] = __builtin_amdgcn_mfma_f32_16x16x32_bf16(al, bh[nt], acc[mt][nt], 0, 0, 0);
      }
    }
  }

  #pragma unroll
  for (int mt = 0; mt < 6; ++mt) {
    #pragma unroll
    for (int nt = 0; nt < 2; ++nt) {
      #pragma unroll
      for (int r = 0; r < 4; ++r) {
        int co = wv * 96 + mt * 16 + qq * 4 + r;
        int px = px0 + nt * 16 + lm;
        out[((size_t)(n * DIMC + co)) * HW + px] = acc[mt][nt][r] + pb[co];
      }
    }
  }
}

extern "C" void kernel_launch(void* const* d_in, const int* in_sizes, int n_in,
                              void* d_out, int out_size, void* d_ws, size_t ws_size,
                              hipStream_t stream) {
  const float* source   = (const float*)d_in[0];
  const float* guidance = (const float*)d_in[1];
  const float* cw[4] = {(const float*)d_in[2],  (const float*)d_in[6],
                        (const float*)d_in[10], (const float*)d_in[14]};
  const float* cb[4] = {(const float*)d_in[3],  (const float*)d_in[7],
                        (const float*)d_in[11], (const float*)d_in[15]};
  const float* ew[4] = {(const float*)d_in[4],  (const float*)d_in[8],
                        (const float*)d_in[12], (const float*)d_in[16]};
  const float* eb[4] = {(const float*)d_in[5],  (const float*)d_in[9],
                        (const float*)d_in[13], (const float*)d_in[17]};
  const float* pw = (const float*)d_in[18];
  const float* pb = (const float*)d_in[19];
  float* out = (float*)d_out;

  float* ws = (float*)d_ws;
  float* g_buf    = ws;                     // 4*3*112*112        = 150528
  float* comp_buf = g_buf + 150528;         // 4*64*112*112       = 3211264
  float* mask_buf = comp_buf + 3211264;     // 4*224*224*9        = 1806336
  float* s2  = mask_buf + 1806336;          // 4*384*28*28        = 1204224
  float* s4  = s2 + 1204224;                // 4*384*56*56        = 4816896
  float* s8  = s4 + 4816896;                // 4*384*112*112      = 19267584
  float* cwT = s8 + 19267584;               // 4*387*64           = 99072
  float* ewT = cwT + 99072;                 // 4*64*9*4*9         = 82944
  short* Whi = (short*)(ewT + 82944);       // 384*416 shorts     = 79872 floats-equiv
  short* Wlo = Whi + DIMC * KPAD;

  prep_cw<<<dim3((CINC * COMPC + 255) / 256, 4), 256, 0, stream>>>(cw[0], cw[1], cw[2], cw[3], cwT);
  prep_ew<<<dim3((COMPC * 9 * 4 * 9 + 255) / 256, 4), 256, 0, stream>>>(ew[0], ew[1], ew[2], ew[3], ewT);
  prep_w<<<(DIMC * KPAD + 255) / 256, 256, 0, stream>>>(pw, Whi, Wlo);

  const float* srcs[4] = {source, s2, s4, s8};
  float* outs[4] = {s2, s4, s8, out};
  const int hs[4] = {14, 28, 56, 112};
  for (int s = 0; s < 4; ++s) {
    int h = hs[s], w = h, hw = h * w;
    int total_r = BATCH * 3 * hw;
    resize_kernel<<<(total_r + 255) / 256, 256, 0, stream>>>(guidance, g_buf, h, w, GSZ / h);
    comp_conv_kernel<<<dim3((hw * 16 + 255) / 256, BATCH), 256, 0, stream>>>(
        srcs[s], g_buf, cwT + s * (CINC * COMPC), cb[s], comp_buf, h, w);
    enc_mask_kernel<<<dim3((hw * 4 + 255) / 256, BATCH), 256, 0, stream>>>(
        comp_buf, ewT + s * (COMPC * 9 * 4 * 9), eb[s], mask_buf, h, w);
    carafe_kernel<<<dim3((hw + 255) / 256, DIMC / 4, BATCH), 256, 0, stream>>>(
        srcs[s], mask_buf, outs[s], h, w);
  }
  final_conv_mfma<<<dim3((GSZ * GSZ) / 32, BATCH), 256, 0, stream>>>(guidance, Whi, Wlo, pb, out);
}